// Round 16
// baseline (256.117 us; speedup 1.0000x reference)
//
#include <hip/hip_runtime.h>
#include <hip/hip_bf16.h>

// DiffAttn: B=4, S=4096, EMB=1024, D=128
//   Q = X@Wq+bq (256 cols = Q1|Q2), K likewise, V = X@Wv+bv (128)
//   out = softmax(Q1K1^T/sqrt(D))@V - lam*softmax(Q2K2^T/sqrt(D))@V
// attn v10: INTRA-BLOCK KEY-SPLIT. 512 thr = 8 waves = 4 q-subs x 2
// key-halves (kh); wave (wq,kh) processes tiles 2j+kh with its own running
// (m,s,o); merged at end via LDS (exp2-weighted, same math as combine).
// -> 16 waves/CU = 4/SIMD (2x occupancy vs R15). 4 x 16KB tile buffers
// {K_br 8K | V 8K}, pair-staged via global_load_lds (R8 maps), R10 body.

typedef __attribute__((ext_vector_type(8))) short bf16x8;    // 8 bf16
typedef __attribute__((ext_vector_type(4))) float f32x4;
typedef __attribute__((ext_vector_type(16))) float f32x16;   // 32x32 C/D

#define MFMA16(a, b, c) __builtin_amdgcn_mfma_f32_16x16x32_bf16((a), (b), (c), 0, 0, 0)
#define MFMA32(a, b, c) __builtin_amdgcn_mfma_f32_32x32x16_bf16((a), (b), (c), 0, 0, 0)

typedef const __attribute__((address_space(1))) void gas_void;
typedef __attribute__((address_space(3))) void las_void;
#define GLOAD16(G, L) __builtin_amdgcn_global_load_lds((gas_void*)(G), (las_void*)(L), 16, 0, 0)

__device__ __forceinline__ unsigned short f2bf(float x) {
    union { float f; unsigned u; } v; v.f = x;   // RNE float->bf16
    return (unsigned short)((v.u + 0x7FFFu + ((v.u >> 16) & 1u)) >> 16);
}
__device__ __forceinline__ unsigned pk2bf(float a, float b) {   // v_cvt_pk_bf16_f32
    __hip_bfloat162 h = __float22bfloat162_rn(float2{a, b});
    union { __hip_bfloat162 h2; unsigned u; } cv; cv.h2 = h;
    return cv.u;
}
__device__ __forceinline__ float fexp2(float x) {   // raw v_exp_f32: D = 2^S0
    float r; asm("v_exp_f32 %0, %1" : "=v"(r) : "v"(x)); return r;
}

// ---------------- W transpose + bf16 convert: Wt[640][1024] ----------------
__global__ __launch_bounds__(256) void wtrans_kernel(
    const float* __restrict__ Wq, const float* __restrict__ Wk,
    const float* __restrict__ Wv, unsigned short* __restrict__ Wt) {
    int tid = blockIdx.x * 256 + threadIdx.x;   // 640*1024 total
    int k = tid & 1023, n = tid >> 10;
    float v;
    if (n < 256)      v = Wq[k * 256 + n];
    else if (n < 512) v = Wk[k * 256 + (n - 256)];
    else              v = Wv[k * 128 + (n - 512)];
    Wt[tid] = f2bf(v);
}

// ---------------- QKV projection GEMM (fp32 X, verified) ----------------
__global__ __launch_bounds__(256) void proj_kernel(
    const float* __restrict__ X, const unsigned short* __restrict__ Wt,
    const float* __restrict__ bq, const float* __restrict__ bk,
    const float* __restrict__ bv,
    unsigned short* __restrict__ Qs, unsigned short* __restrict__ Kb,
    unsigned short* __restrict__ Vb) {
    __shared__ alignas(16) char lds[16384];
    const int nt = blockIdx.y;
    const int m0 = blockIdx.x * 128;
    const int t = threadIdx.x, w = t >> 6, l = t & 63, c = l & 15, g = l >> 4;
    const int wm = w >> 1, wn = w & 1;
    const unsigned short* Wrow = Wt + (long)(nt * 128) * 1024;

    f32x4 acc[4][4];
    const f32x4 fz = {0.f, 0.f, 0.f, 0.f};
#pragma unroll
    for (int i = 0; i < 4; i++)
#pragma unroll
        for (int j = 0; j < 4; j++) acc[i][j] = fz;

    const int srow = t >> 1, sh = t & 1;
    const int sswz = (srow & 7) << 4;
    for (int k0 = 0; k0 < 1024; k0 += 32) {
        const float* xs = X + (long)(m0 + srow) * 1024 + k0 + sh * 16;
        float4 f0 = *(const float4*)(xs + 0);
        float4 f1 = *(const float4*)(xs + 4);
        float4 f2 = *(const float4*)(xs + 8);
        float4 f3 = *(const float4*)(xs + 12);
        const unsigned short* wsc = Wrow + (long)srow * 1024 + k0 + sh * 16;
        uint4 w0 = *(const uint4*)(wsc + 0);
        uint4 w1 = *(const uint4*)(wsc + 8);
        uint4 xa, xb;
        xa.x = pk2bf(f0.x, f0.y); xa.y = pk2bf(f0.z, f0.w);
        xa.z = pk2bf(f1.x, f1.y); xa.w = pk2bf(f1.z, f1.w);
        xb.x = pk2bf(f2.x, f2.y); xb.y = pk2bf(f2.z, f2.w);
        xb.z = pk2bf(f3.x, f3.y); xb.w = pk2bf(f3.z, f3.w);
        int base = srow * 64 + sh * 32;
        *(uint4*)(lds + ((base + 0) ^ sswz)) = xa;
        *(uint4*)(lds + ((base + 16) ^ sswz)) = xb;
        *(uint4*)(lds + 8192 + ((base + 0) ^ sswz)) = w0;
        *(uint4*)(lds + 8192 + ((base + 16) ^ sswz)) = w1;
        __syncthreads();

        bf16x8 af[4];
#pragma unroll
        for (int am = 0; am < 4; am++) {
            int r_ = wm * 64 + am * 16 + c;
            af[am] = *(const bf16x8*)(lds + ((r_ * 64 + g * 16) ^ ((c & 7) << 4)));
        }
#pragma unroll
        for (int bn = 0; bn < 4; bn++) {
            int r_ = wn * 64 + bn * 16 + c;
            bf16x8 bfr = *(const bf16x8*)(lds + 8192 + ((r_ * 64 + g * 16) ^ ((c & 7) << 4)));
#pragma unroll
            for (int am = 0; am < 4; am++) acc[am][bn] = MFMA16(af[am], bfr, acc[am][bn]);
        }
        __syncthreads();
    }

    // Q scale folds 1/sqrt(128) AND log2(e) so attn softmax is pure exp2.
    const float QSCALE = 0.08838834764831845f * 1.4426950408889634f;
    const float* bias; float scale; unsigned short* outp; int ostride, ocol0, boff;
    if (nt < 2)      { bias = bq; boff = nt * 128;       scale = QSCALE; outp = Qs; ostride = 256; ocol0 = nt * 128; }
    else if (nt < 4) { bias = bk; boff = (nt - 2) * 128; scale = 1.0f;   outp = Kb; ostride = 256; ocol0 = (nt - 2) * 128; }
    else             { bias = bv; boff = 0;              scale = 1.0f;   outp = Vb; ostride = 128; ocol0 = 0; }
#pragma unroll
    for (int bn = 0; bn < 4; bn++) {
        int ncol = wn * 64 + bn * 16 + c;
        float bb = bias[boff + ncol];
#pragma unroll
        for (int am = 0; am < 4; am++) {
#pragma unroll
            for (int r = 0; r < 4; r++) {
                long row = m0 + wm * 64 + am * 16 + 4 * g + r;
                outp[row * ostride + ocol0 + ncol] = f2bf((acc[am][bn][r] + bb) * scale);
            }
        }
    }
}

// ---------------- V transpose (LDS-tiled): Vt[b][128][4096] ------------
__global__ __launch_bounds__(256) void vtrans_kernel(
    const unsigned short* __restrict__ Vb, unsigned short* __restrict__ Vt) {
    __shared__ unsigned short lds[64][72];
    const int bid = blockIdx.x;            // 4 b x 64 sb x 2 db = 512
    const int db = bid & 1, sb = (bid >> 1) & 63, b = bid >> 7;
    const int s0 = sb * 64, d0 = db * 64;
    const int t = threadIdx.x;
    const int r = t >> 2, c4 = t & 3;
    const unsigned short* src = Vb + ((long)(b * 4096 + s0 + r)) * 128 + d0;
    uint4 u0 = *(const uint4*)(src + c4 * 8);
    uint4 u1 = *(const uint4*)(src + (c4 + 4) * 8);
    *(uint4*)(&lds[r][c4 * 8]) = u0;
    *(uint4*)(&lds[r][(c4 + 4) * 8]) = u1;
    __syncthreads();
    const int dd = t >> 2;
    unsigned short* dst = Vt + ((long)(b * 128 + d0 + dd)) * 4096 + s0;
#pragma unroll
    for (int cc2 = 0; cc2 < 2; cc2++) {
        int cc = c4 + cc2 * 4;
        unsigned short tmp[8];
#pragma unroll
        for (int j = 0; j < 8; j++) tmp[j] = lds[cc * 8 + j][dd];
        *(uint4*)(dst + cc * 8) = *(const uint4*)tmp;
    }
}

// ---------------- flash diff-attention v10 (intra-block key-split) --------
// 512 thr = 8 waves = 4 q-subs (wq) x 2 key-halves (kh). 128 q x 1 branch.
// LDS: 4 x 16KB tile buffers {K_br[32][256B] rot | V[128][64B] rot} + 2KB ms.
// Step j: vmcnt(0)+barrier; stage tile-pair j+1; wave computes tile 2j+kh.
// Epilogue: kh partials merged via LDS (exp2-weighted), kh=0 writes Po/Ps.
__global__ __launch_bounds__(512, 4) void attn5_kernel(
    const unsigned short* __restrict__ Qs, const unsigned short* __restrict__ Kb,
    const unsigned short* __restrict__ Vt,
    float* __restrict__ Po, float* __restrict__ Ps, int nsplit, int ks) {
    __shared__ alignas(16) char lds[67584];   // 4*16384 + 2048
    const int t = threadIdx.x;
    const int w = t >> 6, l = t & 63, r31 = l & 31, hi = l >> 5;
    const int wq = w >> 1, kh = w & 1;

    const int total = gridDim.x;                 // 256*nsplit (div by 8)
    const int lin = (blockIdx.x & 7) * (total >> 3) + (blockIdx.x >> 3);
    const int qb = lin & 31;
    const int g2 = lin >> 5;                     // (b*nsplit+split)*2 + br
    const int br = g2 & 1;
    const int sp = g2 >> 1;
    const int split = sp % nsplit, b = sp / nsplit;

    const long qrow = (long)b * 4096 + qb * 128 + wq * 32 + r31;
    bf16x8 qf[8];
    const unsigned short* Qp = Qs + qrow * 256 + br * 128 + hi * 8;
#pragma unroll
    for (int ds = 0; ds < 8; ds++) qf[ds] = *(const bf16x8*)(Qp + ds * 16);

    f32x16 o[4];
    const f32x16 oz = {};
#pragma unroll
    for (int dt = 0; dt < 4; dt++) o[dt] = oz;
    float m = -1e30f, s = 0.f;

    // --- staging geometry (512 thr, R8-verified maps): linear LDS dest ---
    const int krow = t >> 4;                       // K row 0..31
    const int ksrc_rot = (((t & 15) * 16) - krow * 16) & 255;
    const int vd = t >> 2;                         // V row (d) 0..127
    const int vcolS = (((t & 3) * 16) - (((vd >> 1) & 3) * 16)) & 63;
    const long kbb = (long)b * 4096;
    const char* kSrc0 = (const char*)Kb + (kbb + krow) * 512 + br * 256 + ksrc_rot;
    const char* vSrc0 = (const char*)Vt + ((long)b * 128 + vd) * 8192 + vcolS;
    char* dst0 = lds + w * 1024;                   // wave-uniform base

    const int kb0 = split * ks;
    const int nt = ks >> 5;                        // 32-key tiles (even)
    const int nj = nt >> 1;                        // tile pairs
#define STAGE(KB_, BUF_)                                                       \
    {                                                                          \
        const char* kp_ = kSrc0 + (long)(KB_)*512;                             \
        const char* vp_ = vSrc0 + (long)(KB_)*2;                               \
        char* d_ = dst0 + (BUF_)*16384;                                        \
        GLOAD16(kp_, d_);                                                      \
        GLOAD16(vp_, d_ + 8192);                                               \
    }

    // --- read offsets (loop-invariant, R10-verified) ---
    int kro[8];
#pragma unroll
    for (int ds = 0; ds < 8; ds++)
        kro[ds] = r31 * 256 + ((ds * 32 + hi * 16 + r31 * 16) & 255);
    int vro0[4], vro1[4];
#pragma unroll
    for (int dt = 0; dt < 4; dt++) {
        int vr = dt * 32 + r31, rot = ((vr >> 1) & 3) * 16;
        vro0[dt] = 8192 + vr * 64 + ((hi * 16 + rot) & 63);
        vro1[dt] = 8192 + vr * 64 + ((32 + hi * 16 + rot) & 63);
    }

    // prologue: stage tile pair 0 (tiles 0,1)
    STAGE(kb0, 0);
    STAGE(kb0 + 32, 1);

    for (int j = 0; j < nj; j++) {
        asm volatile("s_waitcnt vmcnt(0)" ::: "memory");
        __builtin_amdgcn_sched_barrier(0);
        __builtin_amdgcn_s_barrier();
        __builtin_amdgcn_sched_barrier(0);
        if (j + 1 < nj) {
            int base = kb0 + ((j + 1) << 6);
            STAGE(base, (2 * j + 2) & 3);
            STAGE(base + 32, (2 * j + 3) & 3);
        }
        const int ti = 2 * j + kh;
        const char* bufp = lds + (ti & 3) * 16384;

        // ---- QK^T: P^T[key][q], two independent 4-deep chains (R10) ----
        f32x16 pa = oz, pb_ = oz;
        __builtin_amdgcn_s_setprio(1);
#pragma unroll
        for (int ds = 0; ds < 4; ds++) {
            bf16x8 kfa = *(const bf16x8*)(bufp + kro[ds]);
            bf16x8 kfb = *(const bf16x8*)(bufp + kro[ds + 4]);
            pa = MFMA32(kfa, qf[ds], pa);
            pb_ = MFMA32(kfb, qf[ds + 4], pb_);
        }
        __builtin_amdgcn_s_setprio(0);
        f32x16 p;
#pragma unroll
        for (int i = 0; i < 16; i++) p[i] = pa[i] + pb_[i];

        // ---- in-register softmax (exp2 domain; defer-max THR=8) ----
        float x0 = fmaxf(fmaxf(p[0], p[1]), fmaxf(p[2], p[3]));
        float x1 = fmaxf(fmaxf(p[4], p[5]), fmaxf(p[6], p[7]));
        float x2 = fmaxf(fmaxf(p[8], p[9]), fmaxf(p[10], p[11]));
        float x3 = fmaxf(fmaxf(p[12], p[13]), fmaxf(p[14], p[15]));
        float lmx = fmaxf(fmaxf(x0, x1), fmaxf(x2, x3));
        lmx = fmaxf(lmx, __shfl_xor(lmx, 32));
        if (__any(lmx > m + 8.f)) {
            float mn = fmaxf(m, lmx);
            float al = fexp2(m - mn);
            s *= al; m = mn;
#pragma unroll
            for (int dt = 0; dt < 4; dt++) o[dt] *= al;
        }
        float pe[16];
#pragma unroll
        for (int i = 0; i < 16; i++) pe[i] = fexp2(p[i] - m);
        float s0 = (pe[0] + pe[1]) + (pe[2] + pe[3]);
        float s1 = (pe[4] + pe[5]) + (pe[6] + pe[7]);
        float s2 = (pe[8] + pe[9]) + (pe[10] + pe[11]);
        float s3 = (pe[12] + pe[13]) + (pe[14] + pe[15]);
        float ps_ = (s0 + s1) + (s2 + s3);
        ps_ += __shfl_xor(ps_, 32);
        s += ps_;

        // ---- P -> PV B-fragments (cvt_pk + permlane32_swap) ----
        unsigned cA = pk2bf(pe[0], pe[1]), cB = pk2bf(pe[2], pe[3]);
        unsigned cC = pk2bf(pe[4], pe[5]), cD = pk2bf(pe[6], pe[7]);
        asm volatile("v_permlane32_swap_b32 %0, %1" : "+v"(cA), "+v"(cC));
        asm volatile("v_permlane32_swap_b32 %0, %1" : "+v"(cB), "+v"(cD));
        unsigned dA = pk2bf(pe[8], pe[9]), dB = pk2bf(pe[10], pe[11]);
        unsigned dC = pk2bf(pe[12], pe[13]), dD = pk2bf(pe[14], pe[15]);
        asm volatile("v_permlane32_swap_b32 %0, %1" : "+v"(dA), "+v"(dC));
        asm volatile("v_permlane32_swap_b32 %0, %1" : "+v"(dB), "+v"(dD));
        union { uint4 u; bf16x8 v; } pb0, pb1;
        pb0.u = uint4{cA, cB, cC, cD};   // keys 0-15
        pb1.u = uint4{dA, dB, dC, dD};   // keys 16-31

        // ---- PV: O^T[d][q] += V^T-frag x PB ----
        __builtin_amdgcn_s_setprio(1);
#pragma unroll
        for (int dt = 0; dt < 4; dt++) {
            bf16x8 vf0 = *(const bf16x8*)(bufp + vro0[dt]);
            bf16x8 vf1 = *(const bf16x8*)(bufp + vro1[dt]);
            o[dt] = MFMA32(vf0, pb0.v, o[dt]);
            o[dt] = MFMA32(vf1, pb1.v, o[dt]);
        }
        __builtin_amdgcn_s_setprio(0);
    }

    // ---- epilogue: merge kh partials via LDS, kh=0 writes Po/Ps ----
    __syncthreads();   // all waves done reading K/V buffers
    if (kh == 1) {
        char* obase = lds + wq * 16384 + l * 256;
#pragma unroll
        for (int dt = 0; dt < 4; dt++) {
#pragma unroll
            for (int rg = 0; rg < 4; rg++) {
                f32x4 v;
                v[0] = o[dt][rg * 4 + 0];
                v[1] = o[dt][rg * 4 + 1];
                v[2] = o[dt][rg * 4 + 2];
                v[3] = o[dt][rg * 4 + 3];
                *(f32x4*)(obase + (((dt * 4 + rg) * 16 + l * 16) & 255)) = v;
            }
        }
        *(float2*)(lds + 65536 + (wq * 64 + l) * 8) = float2{m, s};
    }
    __syncthreads();
    if (kh == 0) {
        float2 ms1 = *(const float2*)(lds + 65536 + (wq * 64 + l) * 8);
        float mstar = fmaxf(m, ms1.x);
        float a0 = fexp2(m - mstar), a1 = fexp2(ms1.x - mstar);
        s = s * a0 + ms1.y * a1;
        m = mstar;
        const char* obase = lds + wq * 16384 + l * 256;
#pragma unroll
        for (int dt = 0; dt < 4; dt++) {
#pragma unroll
            for (int rg = 0; rg < 4; rg++) {
                f32x4 v1 = *(const f32x4*)(obase + (((dt * 4 + rg) * 16 + l * 16) & 255));
                o[dt][rg * 4 + 0] = o[dt][rg * 4 + 0] * a0 + v1[0] * a1;
                o[dt][rg * 4 + 1] = o[dt][rg * 4 + 1] * a0 + v1[1] * a1;
                o[dt][rg * 4 + 2] = o[dt][rg * 4 + 2] * a0 + v1[2] * a1;
                o[dt][rg * 4 + 3] = o[dt][rg * 4 + 3] * a0 + v1[3] * a1;
            }
        }
        float* po = Po + ((qrow * nsplit + split) * 2 + br) * 128;
#pragma unroll
        for (int dt = 0; dt < 4; dt++) {
#pragma unroll
            for (int rg = 0; rg < 4; rg++) {
                float4 v;   // d = dt*32 + rg*8 + hi*4 + j
                v.x = o[dt][rg * 4 + 0];
                v.y = o[dt][rg * 4 + 1];
                v.z = o[dt][rg * 4 + 2];
                v.w = o[dt][rg * 4 + 3];
                *(float4*)(po + dt * 32 + rg * 8 + hi * 4) = v;
            }
        }
        if (hi == 0)
            *(float2*)(Ps + (qrow * nsplit + split) * 4 + br * 2) = float2{m, s};
    }
#undef STAGE
}

// ---------------- split combine ----------------
__global__ __launch_bounds__(256) void combine_kernel(
    const float* __restrict__ Po, const float* __restrict__ Ps,
    const float* __restrict__ lam_p, float* __restrict__ out, int nsplit) {
    int tid = blockIdx.x * 256 + threadIdx.x;   // 16384 q * 32 threads
    int q = tid >> 5, dq = (tid & 31) * 4;
    float M1 = -1e30f, M2 = -1e30f;
    for (int s = 0; s < nsplit; s++) {
        float4 st = *(const float4*)(Ps + (long)(q * nsplit + s) * 4);
        M1 = fmaxf(M1, st.x); M2 = fmaxf(M2, st.z);
    }
    float S1 = 0.f, S2 = 0.f;
    float a0 = 0.f, a1 = 0.f, a2 = 0.f, a3 = 0.f;
    float b0 = 0.f, b1 = 0.f, b2 = 0.f, b3 = 0.f;
    for (int s = 0; s < nsplit; s++) {
        float4 st = *(const float4*)(Ps + (long)(q * nsplit + s) * 4);
        float w1 = fexp2(st.x - M1), w2 = fexp2(st.z - M2);
        S1 += st.y * w1; S2 += st.w * w2;
        const float* p1 = Po + (((long)q * nsplit + s) * 2 + 0) * 128 + dq;
        const float* p2 = Po + (((long)q * nsplit + s) * 2 + 1) * 128 + dq;
        float4 v1 = *(const float4*)p1;
        float4 v2 = *(const float4*)p2;
        a0 += v1.x * w1; a1 += v1.y * w1; a2 += v1.z * w1; a3 += v1.w * w1;
        b0 += v2.x * w2; b1 += v2.y * w2; b2 += v2.z * w2; b3 += v2.w * w2;
    }
    float lam = *lam_p;
    float i1 = 1.f / S1, i2 = lam / S2;
    float4 v;
    v.x = a0 * i1 - b0 * i2;
    v.y = a1 * i1 - b1 * i2;
    v.z = a2 * i1 - b2 * i2;
    v.w = a3 * i1 - b3 * i2;
    *(float4*)(out + (long)q * 128 + dq) = v;
}

extern "C" void kernel_launch(void* const* d_in, const int* in_sizes, int n_in,
                              void* d_out, int out_size, void* d_ws, size_t ws_size,
                              hipStream_t stream) {
    const float* X   = (const float*)d_in[0];
    const float* lam = (const float*)d_in[1];
    const float* Wq  = (const float*)d_in[2];
    const float* bq  = (const float*)d_in[3];
    const float* Wk  = (const float*)d_in[4];
    const float* bk  = (const float*)d_in[5];
    const float* Wv  = (const float*)d_in[6];
    const float* bv  = (const float*)d_in[7];
    char* ws = (char*)d_ws;
    // ws: Qs 8M | Kb 8M | Vb 4M | Vt 4M | Wt 1.25M | @26M: Po, Ps
    unsigned short* Qs = (unsigned short*)(ws);
    unsigned short* Kb = (unsigned short*)(ws + (8u << 20));
    unsigned short* Vb = (unsigned short*)(ws + (16u << 20));
    unsigned short* Vt = (unsigned short*)(ws + (20u << 20));
    unsigned short* Wt = (unsigned short*)(ws + (24u << 20));
    const size_t base = (size_t)26 << 20;
    const size_t NQ = 16384;
    int nsplit = 1;
    if (ws_size >= base + NQ * 4 * 2 * 128 * 4 + NQ * 4 * 4 * 4)      nsplit = 4;
    else if (ws_size >= base + NQ * 2 * 2 * 128 * 4 + NQ * 2 * 4 * 4) nsplit = 2;
    float* Po = (float*)(ws + base);
    float* Ps = (float*)(ws + base + NQ * (size_t)nsplit * 2 * 128 * 4);

    wtrans_kernel<<<2560, 256, 0, stream>>>(Wq, Wk, Wv, Wt);
    proj_kernel<<<dim3(128, 5), 256, 0, stream>>>(X, Wt, bq, bk, bv, Qs, Kb, Vb);
    vtrans_kernel<<<512, 256, 0, stream>>>(Vb, Vt);
    attn5_kernel<<<256 * nsplit, 512, 0, stream>>>(Qs, Kb, Vt, Po, Ps,
                                                   nsplit, 4096 / nsplit);
    combine_kernel<<<2048, 256, 0, stream>>>(Po, Ps, lam, (float*)d_out, nsplit);
}

// Round 17
// 179.187 us; speedup vs baseline: 1.4293x; 1.4293x over previous
//
#include <hip/hip_runtime.h>
#include <hip/hip_bf16.h>

// DiffAttn: B=4, S=4096, EMB=1024, D=128
//   Q = X@Wq+bq (256 cols = Q1|Q2), K likewise, V = X@Wv+bv (128)
//   out = softmax(Q1K1^T/sqrt(D))@V - lam*softmax(Q2K2^T/sqrt(D))@V
// attn v10.1: R16's intra-block key-split with the REGISTER CAP FIXED:
// __launch_bounds__(512) (no min-waves arg). R16's (512,4) capped VGPR at
// 64 -> ~60 regs of per-wave state spilled to scratch (FETCH 22->230 MB,
// 2.5x slower). Natural allocation ~112 <= 128 lets 2 blocks/CU x 8 waves
// = 4 waves/SIMD co-reside (LDS 66KB). Structure verified correct in R16.

typedef __attribute__((ext_vector_type(8))) short bf16x8;    // 8 bf16
typedef __attribute__((ext_vector_type(4))) float f32x4;
typedef __attribute__((ext_vector_type(16))) float f32x16;   // 32x32 C/D

#define MFMA16(a, b, c) __builtin_amdgcn_mfma_f32_16x16x32_bf16((a), (b), (c), 0, 0, 0)
#define MFMA32(a, b, c) __builtin_amdgcn_mfma_f32_32x32x16_bf16((a), (b), (c), 0, 0, 0)

typedef const __attribute__((address_space(1))) void gas_void;
typedef __attribute__((address_space(3))) void las_void;
#define GLOAD16(G, L) __builtin_amdgcn_global_load_lds((gas_void*)(G), (las_void*)(L), 16, 0, 0)

__device__ __forceinline__ unsigned short f2bf(float x) {
    union { float f; unsigned u; } v; v.f = x;   // RNE float->bf16
    return (unsigned short)((v.u + 0x7FFFu + ((v.u >> 16) & 1u)) >> 16);
}
__device__ __forceinline__ unsigned pk2bf(float a, float b) {   // v_cvt_pk_bf16_f32
    __hip_bfloat162 h = __float22bfloat162_rn(float2{a, b});
    union { __hip_bfloat162 h2; unsigned u; } cv; cv.h2 = h;
    return cv.u;
}
__device__ __forceinline__ float fexp2(float x) {   // raw v_exp_f32: D = 2^S0
    float r; asm("v_exp_f32 %0, %1" : "=v"(r) : "v"(x)); return r;
}

// ---------------- W transpose + bf16 convert: Wt[640][1024] ----------------
__global__ __launch_bounds__(256) void wtrans_kernel(
    const float* __restrict__ Wq, const float* __restrict__ Wk,
    const float* __restrict__ Wv, unsigned short* __restrict__ Wt) {
    int tid = blockIdx.x * 256 + threadIdx.x;   // 640*1024 total
    int k = tid & 1023, n = tid >> 10;
    float v;
    if (n < 256)      v = Wq[k * 256 + n];
    else if (n < 512) v = Wk[k * 256 + (n - 256)];
    else              v = Wv[k * 128 + (n - 512)];
    Wt[tid] = f2bf(v);
}

// ---------------- QKV projection GEMM (fp32 X, verified) ----------------
__global__ __launch_bounds__(256) void proj_kernel(
    const float* __restrict__ X, const unsigned short* __restrict__ Wt,
    const float* __restrict__ bq, const float* __restrict__ bk,
    const float* __restrict__ bv,
    unsigned short* __restrict__ Qs, unsigned short* __restrict__ Kb,
    unsigned short* __restrict__ Vb) {
    __shared__ alignas(16) char lds[16384];
    const int nt = blockIdx.y;
    const int m0 = blockIdx.x * 128;
    const int t = threadIdx.x, w = t >> 6, l = t & 63, c = l & 15, g = l >> 4;
    const int wm = w >> 1, wn = w & 1;
    const unsigned short* Wrow = Wt + (long)(nt * 128) * 1024;

    f32x4 acc[4][4];
    const f32x4 fz = {0.f, 0.f, 0.f, 0.f};
#pragma unroll
    for (int i = 0; i < 4; i++)
#pragma unroll
        for (int j = 0; j < 4; j++) acc[i][j] = fz;

    const int srow = t >> 1, sh = t & 1;
    const int sswz = (srow & 7) << 4;
    for (int k0 = 0; k0 < 1024; k0 += 32) {
        const float* xs = X + (long)(m0 + srow) * 1024 + k0 + sh * 16;
        float4 f0 = *(const float4*)(xs + 0);
        float4 f1 = *(const float4*)(xs + 4);
        float4 f2 = *(const float4*)(xs + 8);
        float4 f3 = *(const float4*)(xs + 12);
        const unsigned short* wsc = Wrow + (long)srow * 1024 + k0 + sh * 16;
        uint4 w0 = *(const uint4*)(wsc + 0);
        uint4 w1 = *(const uint4*)(wsc + 8);
        uint4 xa, xb;
        xa.x = pk2bf(f0.x, f0.y); xa.y = pk2bf(f0.z, f0.w);
        xa.z = pk2bf(f1.x, f1.y); xa.w = pk2bf(f1.z, f1.w);
        xb.x = pk2bf(f2.x, f2.y); xb.y = pk2bf(f2.z, f2.w);
        xb.z = pk2bf(f3.x, f3.y); xb.w = pk2bf(f3.z, f3.w);
        int base = srow * 64 + sh * 32;
        *(uint4*)(lds + ((base + 0) ^ sswz)) = xa;
        *(uint4*)(lds + ((base + 16) ^ sswz)) = xb;
        *(uint4*)(lds + 8192 + ((base + 0) ^ sswz)) = w0;
        *(uint4*)(lds + 8192 + ((base + 16) ^ sswz)) = w1;
        __syncthreads();

        bf16x8 af[4];
#pragma unroll
        for (int am = 0; am < 4; am++) {
            int r_ = wm * 64 + am * 16 + c;
            af[am] = *(const bf16x8*)(lds + ((r_ * 64 + g * 16) ^ ((c & 7) << 4)));
        }
#pragma unroll
        for (int bn = 0; bn < 4; bn++) {
            int r_ = wn * 64 + bn * 16 + c;
            bf16x8 bfr = *(const bf16x8*)(lds + 8192 + ((r_ * 64 + g * 16) ^ ((c & 7) << 4)));
#pragma unroll
            for (int am = 0; am < 4; am++) acc[am][bn] = MFMA16(af[am], bfr, acc[am][bn]);
        }
        __syncthreads();
    }

    // Q scale folds 1/sqrt(128) AND log2(e) so attn softmax is pure exp2.
    const float QSCALE = 0.08838834764831845f * 1.4426950408889634f;
    const float* bias; float scale; unsigned short* outp; int ostride, ocol0, boff;
    if (nt < 2)      { bias = bq; boff = nt * 128;       scale = QSCALE; outp = Qs; ostride = 256; ocol0 = nt * 128; }
    else if (nt < 4) { bias = bk; boff = (nt - 2) * 128; scale = 1.0f;   outp = Kb; ostride = 256; ocol0 = (nt - 2) * 128; }
    else             { bias = bv; boff = 0;              scale = 1.0f;   outp = Vb; ostride = 128; ocol0 = 0; }
#pragma unroll
    for (int bn = 0; bn < 4; bn++) {
        int ncol = wn * 64 + bn * 16 + c;
        float bb = bias[boff + ncol];
#pragma unroll
        for (int am = 0; am < 4; am++) {
#pragma unroll
            for (int r = 0; r < 4; r++) {
                long row = m0 + wm * 64 + am * 16 + 4 * g + r;
                outp[row * ostride + ocol0 + ncol] = f2bf((acc[am][bn][r] + bb) * scale);
            }
        }
    }
}

// ---------------- V transpose (LDS-tiled): Vt[b][128][4096] ------------
__global__ __launch_bounds__(256) void vtrans_kernel(
    const unsigned short* __restrict__ Vb, unsigned short* __restrict__ Vt) {
    __shared__ unsigned short lds[64][72];
    const int bid = blockIdx.x;            // 4 b x 64 sb x 2 db = 512
    const int db = bid & 1, sb = (bid >> 1) & 63, b = bid >> 7;
    const int s0 = sb * 64, d0 = db * 64;
    const int t = threadIdx.x;
    const int r = t >> 2, c4 = t & 3;
    const unsigned short* src = Vb + ((long)(b * 4096 + s0 + r)) * 128 + d0;
    uint4 u0 = *(const uint4*)(src + c4 * 8);
    uint4 u1 = *(const uint4*)(src + (c4 + 4) * 8);
    *(uint4*)(&lds[r][c4 * 8]) = u0;
    *(uint4*)(&lds[r][(c4 + 4) * 8]) = u1;
    __syncthreads();
    const int dd = t >> 2;
    unsigned short* dst = Vt + ((long)(b * 128 + d0 + dd)) * 4096 + s0;
#pragma unroll
    for (int cc2 = 0; cc2 < 2; cc2++) {
        int cc = c4 + cc2 * 4;
        unsigned short tmp[8];
#pragma unroll
        for (int j = 0; j < 8; j++) tmp[j] = lds[cc * 8 + j][dd];
        *(uint4*)(dst + cc * 8) = *(const uint4*)tmp;
    }
}

// ---------------- flash diff-attention v10.1 (intra-block key-split) ------
// 512 thr = 8 waves = 4 q-subs (wq) x 2 key-halves (kh). 128 q x 1 branch.
// LDS: 4 x 16KB tile buffers {K_br[32][256B] rot | V[128][64B] rot} + 2KB ms.
// Step j: vmcnt(0)+barrier; stage tile-pair j+1; wave computes tile 2j+kh.
// Epilogue: kh partials merged via LDS (exp2-weighted), kh=0 writes Po/Ps.
__global__ __launch_bounds__(512) void attn5_kernel(
    const unsigned short* __restrict__ Qs, const unsigned short* __restrict__ Kb,
    const unsigned short* __restrict__ Vt,
    float* __restrict__ Po, float* __restrict__ Ps, int nsplit, int ks) {
    __shared__ alignas(16) char lds[67584];   // 4*16384 + 2048
    const int t = threadIdx.x;
    const int w = t >> 6, l = t & 63, r31 = l & 31, hi = l >> 5;
    const int wq = w >> 1, kh = w & 1;

    const int total = gridDim.x;                 // 256*nsplit (div by 8)
    const int lin = (blockIdx.x & 7) * (total >> 3) + (blockIdx.x >> 3);
    const int qb = lin & 31;
    const int g2 = lin >> 5;                     // (b*nsplit+split)*2 + br
    const int br = g2 & 1;
    const int sp = g2 >> 1;
    const int split = sp % nsplit, b = sp / nsplit;

    const long qrow = (long)b * 4096 + qb * 128 + wq * 32 + r31;
    bf16x8 qf[8];
    const unsigned short* Qp = Qs + qrow * 256 + br * 128 + hi * 8;
#pragma unroll
    for (int ds = 0; ds < 8; ds++) qf[ds] = *(const bf16x8*)(Qp + ds * 16);

    f32x16 o[4];
    const f32x16 oz = {};
#pragma unroll
    for (int dt = 0; dt < 4; dt++) o[dt] = oz;
    float m = -1e30f, s = 0.f;

    // --- staging geometry (512 thr, R8-verified maps): linear LDS dest ---
    const int krow = t >> 4;                       // K row 0..31
    const int ksrc_rot = (((t & 15) * 16) - krow * 16) & 255;
    const int vd = t >> 2;                         // V row (d) 0..127
    const int vcolS = (((t & 3) * 16) - (((vd >> 1) & 3) * 16)) & 63;
    const long kbb = (long)b * 4096;
    const char* kSrc0 = (const char*)Kb + (kbb + krow) * 512 + br * 256 + ksrc_rot;
    const char* vSrc0 = (const char*)Vt + ((long)b * 128 + vd) * 8192 + vcolS;
    char* dst0 = lds + w * 1024;                   // wave-uniform base

    const int kb0 = split * ks;
    const int nt = ks >> 5;                        // 32-key tiles (even)
    const int nj = nt >> 1;                        // tile pairs
#define STAGE(KB_, BUF_)                                                       \
    {                                                                          \
        const char* kp_ = kSrc0 + (long)(KB_)*512;                             \
        const char* vp_ = vSrc0 + (long)(KB_)*2;                               \
        char* d_ = dst0 + (BUF_)*16384;                                        \
        GLOAD16(kp_, d_);                                                      \
        GLOAD16(vp_, d_ + 8192);                                               \
    }

    // --- read offsets (loop-invariant, R10-verified) ---
    int kro[8];
#pragma unroll
    for (int ds = 0; ds < 8; ds++)
        kro[ds] = r31 * 256 + ((ds * 32 + hi * 16 + r31 * 16) & 255);
    int vro0[4], vro1[4];
#pragma unroll
    for (int dt = 0; dt < 4; dt++) {
        int vr = dt * 32 + r31, rot = ((vr >> 1) & 3) * 16;
        vro0[dt] = 8192 + vr * 64 + ((hi * 16 + rot) & 63);
        vro1[dt] = 8192 + vr * 64 + ((32 + hi * 16 + rot) & 63);
    }

    // prologue: stage tile pair 0 (tiles 0,1)
    STAGE(kb0, 0);
    STAGE(kb0 + 32, 1);

    for (int j = 0; j < nj; j++) {
        asm volatile("s_waitcnt vmcnt(0)" ::: "memory");
        __builtin_amdgcn_sched_barrier(0);
        __builtin_amdgcn_s_barrier();
        __builtin_amdgcn_sched_barrier(0);
        if (j + 1 < nj) {
            int base = kb0 + ((j + 1) << 6);
            STAGE(base, (2 * j + 2) & 3);
            STAGE(base + 32, (2 * j + 3) & 3);
        }
        const int ti = 2 * j + kh;
        const char* bufp = lds + (ti & 3) * 16384;

        // ---- QK^T: P^T[key][q], two independent 4-deep chains (R10) ----
        f32x16 pa = oz, pb_ = oz;
        __builtin_amdgcn_s_setprio(1);
#pragma unroll
        for (int ds = 0; ds < 4; ds++) {
            bf16x8 kfa = *(const bf16x8*)(bufp + kro[ds]);
            bf16x8 kfb = *(const bf16x8*)(bufp + kro[ds + 4]);
            pa = MFMA32(kfa, qf[ds], pa);
            pb_ = MFMA32(kfb, qf[ds + 4], pb_);
        }
        __builtin_amdgcn_s_setprio(0);
        f32x16 p;
#pragma unroll
        for (int i = 0; i < 16; i++) p[i] = pa[i] + pb_[i];

        // ---- in-register softmax (exp2 domain; defer-max THR=8) ----
        float x0 = fmaxf(fmaxf(p[0], p[1]), fmaxf(p[2], p[3]));
        float x1 = fmaxf(fmaxf(p[4], p[5]), fmaxf(p[6], p[7]));
        float x2 = fmaxf(fmaxf(p[8], p[9]), fmaxf(p[10], p[11]));
        float x3 = fmaxf(fmaxf(p[12], p[13]), fmaxf(p[14], p[15]));
        float lmx = fmaxf(fmaxf(x0, x1), fmaxf(x2, x3));
        lmx = fmaxf(lmx, __shfl_xor(lmx, 32));
        if (__any(lmx > m + 8.f)) {
            float mn = fmaxf(m, lmx);
            float al = fexp2(m - mn);
            s *= al; m = mn;
#pragma unroll
            for (int dt = 0; dt < 4; dt++) o[dt] *= al;
        }
        float pe[16];
#pragma unroll
        for (int i = 0; i < 16; i++) pe[i] = fexp2(p[i] - m);
        float s0 = (pe[0] + pe[1]) + (pe[2] + pe[3]);
        float s1 = (pe[4] + pe[5]) + (pe[6] + pe[7]);
        float s2 = (pe[8] + pe[9]) + (pe[10] + pe[11]);
        float s3 = (pe[12] + pe[13]) + (pe[14] + pe[15]);
        float ps_ = (s0 + s1) + (s2 + s3);
        ps_ += __shfl_xor(ps_, 32);
        s += ps_;

        // ---- P -> PV B-fragments (cvt_pk + permlane32_swap) ----
        unsigned cA = pk2bf(pe[0], pe[1]), cB = pk2bf(pe[2], pe[3]);
        unsigned cC = pk2bf(pe[4], pe[5]), cD = pk2bf(pe[6], pe[7]);
        asm volatile("v_permlane32_swap_b32 %0, %1" : "+v"(cA), "+v"(cC));
        asm volatile("v_permlane32_swap_b32 %0, %1" : "+v"(cB), "+v"(cD));
        unsigned dA = pk2bf(pe[8], pe[9]), dB = pk2bf(pe[10], pe[11]);
        unsigned dC = pk2bf(pe[12], pe[13]), dD = pk2bf(pe[14], pe[15]);
        asm volatile("v_permlane32_swap_b32 %0, %1" : "+v"(dA), "+v"(dC));
        asm volatile("v_permlane32_swap_b32 %0, %1" : "+v"(dB), "+v"(dD));
        union { uint4 u; bf16x8 v; } pb0, pb1;
        pb0.u = uint4{cA, cB, cC, cD};   // keys 0-15
        pb1.u = uint4{dA, dB, dC, dD};   // keys 16-31

        // ---- PV: O^T[d][q] += V^T-frag x PB ----
        __builtin_amdgcn_s_setprio(1);
#pragma unroll
        for (int dt = 0; dt < 4; dt++) {
            bf16x8 vf0 = *(const bf16x8*)(bufp + vro0[dt]);
            bf16x8 vf1 = *(const bf16x8*)(bufp + vro1[dt]);
            o[dt] = MFMA32(vf0, pb0.v, o[dt]);
            o[dt] = MFMA32(vf1, pb1.v, o[dt]);
        }
        __builtin_amdgcn_s_setprio(0);
    }

    // ---- epilogue: merge kh partials via LDS, kh=0 writes Po/Ps ----
    __syncthreads();   // all waves done reading K/V buffers
    if (kh == 1) {
        char* obase = lds + wq * 16384 + l * 256;
#pragma unroll
        for (int dt = 0; dt < 4; dt++) {
#pragma unroll
            for (int rg = 0; rg < 4; rg++) {
                f32x4 v;
                v[0] = o[dt][rg * 4 + 0];
                v[1] = o[dt][rg * 4 + 1];
                v[2] = o[dt][rg * 4 + 2];
                v[3] = o[dt][rg * 4 + 3];
                *(f32x4*)(obase + (((dt * 4 + rg) * 16 + l * 16) & 255)) = v;
            }
        }
        *(float2*)(lds + 65536 + (wq * 64 + l) * 8) = float2{m, s};
    }
    __syncthreads();
    if (kh == 0) {
        float2 ms1 = *(const float2*)(lds + 65536 + (wq * 64 + l) * 8);
        float mstar = fmaxf(m, ms1.x);
        float a0 = fexp2(m - mstar), a1 = fexp2(ms1.x - mstar);
        s = s * a0 + ms1.y * a1;
        m = mstar;
        const char* obase = lds + wq * 16384 + l * 256;
#pragma unroll
        for (int dt = 0; dt < 4; dt++) {
#pragma unroll
            for (int rg = 0; rg < 4; rg++) {
                f32x4 v1 = *(const f32x4*)(obase + (((dt * 4 + rg) * 16 + l * 16) & 255));
                o[dt][rg * 4 + 0] = o[dt][rg * 4 + 0] * a0 + v1[0] * a1;
                o[dt][rg * 4 + 1] = o[dt][rg * 4 + 1] * a0 + v1[1] * a1;
                o[dt][rg * 4 + 2] = o[dt][rg * 4 + 2] * a0 + v1[2] * a1;
                o[dt][rg * 4 + 3] = o[dt][rg * 4 + 3] * a0 + v1[3] * a1;
            }
        }
        float* po = Po + ((qrow * nsplit + split) * 2 + br) * 128;
#pragma unroll
        for (int dt = 0; dt < 4; dt++) {
#pragma unroll
            for (int rg = 0; rg < 4; rg++) {
                float4 v;   // d = dt*32 + rg*8 + hi*4 + j
                v.x = o[dt][rg * 4 + 0];
                v.y = o[dt][rg * 4 + 1];
                v.z = o[dt][rg * 4 + 2];
                v.w = o[dt][rg * 4 + 3];
                *(float4*)(po + dt * 32 + rg * 8 + hi * 4) = v;
            }
        }
        if (hi == 0)
            *(float2*)(Ps + (qrow * nsplit + split) * 4 + br * 2) = float2{m, s};
    }
#undef STAGE
}

// ---------------- split combine ----------------
__global__ __launch_bounds__(256) void combine_kernel(
    const float* __restrict__ Po, const float* __restrict__ Ps,
    const float* __restrict__ lam_p, float* __restrict__ out, int nsplit) {
    int tid = blockIdx.x * 256 + threadIdx.x;   // 16384 q * 32 threads
    int q = tid >> 5, dq = (tid & 31) * 4;
    float M1 = -1e30f, M2 = -1e30f;
    for (int s = 0; s < nsplit; s++) {
        float4 st = *(const float4*)(Ps + (long)(q * nsplit + s) * 4);
        M1 = fmaxf(M1, st.x); M2 = fmaxf(M2, st.z);
    }
    float S1 = 0.f, S2 = 0.f;
    float a0 = 0.f, a1 = 0.f, a2 = 0.f, a3 = 0.f;
    float b0 = 0.f, b1 = 0.f, b2 = 0.f, b3 = 0.f;
    for (int s = 0; s < nsplit; s++) {
        float4 st = *(const float4*)(Ps + (long)(q * nsplit + s) * 4);
        float w1 = fexp2(st.x - M1), w2 = fexp2(st.z - M2);
        S1 += st.y * w1; S2 += st.w * w2;
        const float* p1 = Po + (((long)q * nsplit + s) * 2 + 0) * 128 + dq;
        const float* p2 = Po + (((long)q * nsplit + s) * 2 + 1) * 128 + dq;
        float4 v1 = *(const float4*)p1;
        float4 v2 = *(const float4*)p2;
        a0 += v1.x * w1; a1 += v1.y * w1; a2 += v1.z * w1; a3 += v1.w * w1;
        b0 += v2.x * w2; b1 += v2.y * w2; b2 += v2.z * w2; b3 += v2.w * w2;
    }
    float lam = *lam_p;
    float i1 = 1.f / S1, i2 = lam / S2;
    float4 v;
    v.x = a0 * i1 - b0 * i2;
    v.y = a1 * i1 - b1 * i2;
    v.z = a2 * i1 - b2 * i2;
    v.w = a3 * i1 - b3 * i2;
    *(float4*)(out + (long)q * 128 + dq) = v;
}

extern "C" void kernel_launch(void* const* d_in, const int* in_sizes, int n_in,
                              void* d_out, int out_size, void* d_ws, size_t ws_size,
                              hipStream_t stream) {
    const float* X   = (const float*)d_in[0];
    const float* lam = (const float*)d_in[1];
    const float* Wq  = (const float*)d_in[2];
    const float* bq  = (const float*)d_in[3];
    const float* Wk  = (const float*)d_in[4];
    const float* bk  = (const float*)d_in[5];
    const float* Wv  = (const float*)d_in[6];
    const float* bv  = (const float*)d_in[7];
    char* ws = (char*)d_ws;
    // ws: Qs 8M | Kb 8M | Vb 4M | Vt 4M | Wt 1.25M | @26M: Po, Ps
    unsigned short* Qs = (unsigned short*)(ws);
    unsigned short* Kb = (unsigned short*)(ws + (8u << 20));
    unsigned short* Vb = (unsigned short*)(ws + (16u << 20));
    unsigned short* Vt = (unsigned short*)(ws + (20u << 20));
    unsigned short* Wt = (unsigned short*)(ws + (24u << 20));
    const size_t base = (size_t)26 << 20;
    const size_t NQ = 16384;
    int nsplit = 1;
    if (ws_size >= base + NQ * 4 * 2 * 128 * 4 + NQ * 4 * 4 * 4)      nsplit = 4;
    else if (ws_size >= base + NQ * 2 * 2 * 128 * 4 + NQ * 2 * 4 * 4) nsplit = 2;
    float* Po = (float*)(ws + base);
    float* Ps = (float*)(ws + base + NQ * (size_t)nsplit * 2 * 128 * 4);

    wtrans_kernel<<<2560, 256, 0, stream>>>(Wq, Wk, Wv, Wt);
    proj_kernel<<<dim3(128, 5), 256, 0, stream>>>(X, Wt, bq, bk, bv, Qs, Kb, Vb);
    vtrans_kernel<<<512, 256, 0, stream>>>(Vb, Vt);
    attn5_kernel<<<256 * nsplit, 512, 0, stream>>>(Qs, Kb, Vt, Po, Ps,
                                                   nsplit, 4096 / nsplit);
    combine_kernel<<<2048, 256, 0, stream>>>(Po, Ps, lam, (float*)d_out, nsplit);
}